// Round 14
// baseline (131.225 us; speedup 1.0000x reference)
//
#include <hip/hip_runtime.h>

// ---------- types ----------
typedef short short8 __attribute__((ext_vector_type(8)));        // 8 bf16 MFMA A/B frag
typedef float floatx4 __attribute__((ext_vector_type(4)));       // MFMA C/D frag
typedef float float2v __attribute__((ext_vector_type(2)));       // v_pk_fma_f32 operand

__device__ __forceinline__ unsigned short f2bf(float f) {
    unsigned u = __float_as_uint(f);
    u += 0x7fffu + ((u >> 16) & 1u);   // RNE
    return (unsigned short)(u >> 16);
}
__device__ __forceinline__ float bf2f(unsigned short b) {
    unsigned u = (unsigned)b << 16;
    return __uint_as_float(u);
}

#define MFMA16(a, b, c)  __builtin_amdgcn_mfma_f32_16x16x32_bf16((a), (b), (c), 0, 0, 0)

// ---------- ws layout (bytes) ----------
// Ledger: r0=134.3 | coop=wash | v9 LDS-flash=+4 | NSPLIT32(v8)=+2 |
// r6 = 128.4 BEST | r7 gq-x2deep=+3.1 REV | r9 v13 gl_lds=+8 REV |
// r11 NSPLIT32(v12)=+4.1 REV | r12 T15 ping-pong=+2.7 REV (overlap refuted
// by 4 instruments: TLP x2, staging x2, intra-wave; in-order issue slot
// serializes VALU/MFMA within a wave). PROBES: fills=87, T_flash_v12=20.9
// (MFMA-busy 7.1 = theoretical min; VALU-busy 11.8 = CRITICAL PATH),
// T_gq=8.0, prep+out+gaps=12.5.
// R13/R14 (r13 infra-failed, resubmit): cut VALU INSTRUCTION COUNT.
// flash v16 = v12 structure + packed finish: {numv,lsum} as float2 acc,
// nl += {p,p}*{u,1.0} -> v_pk_fma_f32 (gfx950 has it; it IS the 157TF
// packed-fp32 path). numv half identical fmac; lsum half fma(p,1,l) = add
// (exact). BIT-IDENTICAL, -16 VALU insts/sub-tile off the measured
// critical path. Single variable.
static constexpr size_t Q_OFF    = 0;                    // q*QSCALE packed bf16 2 MB
static constexpr size_t K_OFF    = 2u << 20;             // k packed bf16        2 MB
static constexpr size_t U_OFF    = 4u << 20;             // u fp32 [8192]       32 KB
static constexpr size_t WFCT_OFF = U_OFF + 32768;        // W_fc packed bf16   256 KB
static constexpr size_t WGT_OFF  = WFCT_OFF + 262144;    // W_gate packed bf16
static constexpr size_t WQT_OFF  = WGT_OFF + 262144;     // W_q packed bf16     32 KB
static constexpr size_t WKT_OFF  = WQT_OFF + 32768;      // W_k packed bf16
static constexpr size_t WVO_OFF  = WKT_OFF + 32768;      // wvo fp32 [128] + c0
static constexpr size_t PB_OFF   = 5u << 20;             // partials float2 [8192][16] 1 MB

static constexpr int NSPLIT = 16;
// log2(e)/sqrt(128): folded into stored q so P = exp2(S)
static constexpr float QSCALE = 0.1275174308f;

// ---------- K1: weights -> MFMA-packed bf16 + wvo = W_v @ W_out GEMV (r0 exact) ----------
__global__ void k_prep(const float* __restrict__ wfc, const float* __restrict__ wg,
                       const float* __restrict__ wq, const float* __restrict__ wk,
                       const float* __restrict__ wv, const float* __restrict__ wout,
                       const float* __restrict__ bv,
                       unsigned short* __restrict__ dfc, unsigned short* __restrict__ dg,
                       unsigned short* __restrict__ dq, unsigned short* __restrict__ dk,
                       float* __restrict__ wvo) {
    if (blockIdx.x == 1216) {
        int t = threadIdx.x;
        if (t < 128) {
            float s = 0.f;
            for (int j = 0; j < 128; ++j) s += wv[t * 128 + j] * wout[j];
            wvo[t] = s;
        } else if (t == 128) {
            float s = 0.f;
            for (int j = 0; j < 128; ++j) s += bv[j] * wout[j];
            wvo[128] = s;   // c0
        }
        return;
    }
    int i = blockIdx.x * 256 + threadIdx.x;
    const float* s; unsigned short* d; int base, nchunk;
    if (i < 131072)      { s = wfc; d = dfc; nchunk = 32; base = 0; }
    else if (i < 262144) { s = wg;  d = dg;  nchunk = 32; base = 131072; }
    else if (i < 278528) { s = wq;  d = dq;  nchunk = 4;  base = 262144; }
    else if (i < 294912) { s = wk;  d = dk;  nchunk = 4;  base = 278528; }
    else return;
    int j = i - base;
    int kk = j >> 7, nn = j & 127;        // source W[kk][nn], row-major K x 128
    int t = nn >> 4, lr = nn & 15;
    int c = kk >> 5, lk = (kk >> 3) & 3, e = kk & 7;
    d[(((t * nchunk + c) * 64) + lr + 16 * lk) * 8 + e] = f2bf(s[j]);
}

// ---------- K2: fused gated-linear + QK + u (r6-exact, 128.4-verified) ----------
__global__ __launch_bounds__(512) void k_gq(const float* __restrict__ x,
                                            const unsigned short* __restrict__ wfcp,
                                            const unsigned short* __restrict__ wgp,
                                            const float* __restrict__ bfc,
                                            const float* __restrict__ bg,
                                            const unsigned short* __restrict__ wqp,
                                            const unsigned short* __restrict__ wkp,
                                            const float* __restrict__ bq,
                                            const float* __restrict__ bk,
                                            const float* __restrict__ wvo,
                                            unsigned short* __restrict__ qpk,
                                            unsigned short* __restrict__ kpk,
                                            float* __restrict__ ug) {
    __shared__ __align__(16) unsigned short xs[2][32 * 136];
    __shared__ __align__(16) float gbuf[32 * 132];
    __shared__ __align__(16) unsigned short hs[32 * 136];
    const int tid = threadIdx.x;
    const int i0 = blockIdx.x * 32;
    const int w = tid >> 6, lane = tid & 63;
    const int lr = lane & 15, lk = lane >> 4;

    const int isg = (w >= 4);
    const int wq4 = w & 3;                 // 0..3: which 32-col group
    const unsigned short* wp = isg ? wgp : wfcp;

    floatx4 acc[2][2];
#pragma unroll
    for (int mt = 0; mt < 2; ++mt)
#pragma unroll
        for (int nt = 0; nt < 2; ++nt) acc[mt][nt] = (floatx4)0.0f;

    const int srow = tid >> 4, se = tid & 15;   // 32 rows x 16 thr, 8 floats each
    const float* gp0 = x + (size_t)(i0 + srow) * 1024 + se * 8;
    float4 ra = *(const float4*)gp0;
    float4 rb = *(const float4*)(gp0 + 4);

    // bfr[kc&1][ks][nt]: current/next kc weight frags (64 VGPR), preload kc=0
    short8 bfr[2][4][2];
#pragma unroll
    for (int ks = 0; ks < 4; ++ks)
#pragma unroll
        for (int nt = 0; nt < 2; ++nt)
            bfr[0][ks][nt] = *(const short8*)(wp + ((((size_t)(wq4 * 2 + nt)) * 32 + ks) * 64 + lane) * 8);

#pragma unroll
    for (int kc = 0; kc < 8; ++kc) {
        {   // commit prefetched chunk to LDS buf kc&1 (fp32 -> bf16)
            short8 t;
            unsigned short* tp = (unsigned short*)&t;
            tp[0] = f2bf(ra.x); tp[1] = f2bf(ra.y); tp[2] = f2bf(ra.z); tp[3] = f2bf(ra.w);
            tp[4] = f2bf(rb.x); tp[5] = f2bf(rb.y); tp[6] = f2bf(rb.z); tp[7] = f2bf(rb.w);
            *(short8*)(xs[kc & 1] + srow * 136 + se * 8) = t;
        }
        if (kc < 7) {
            const float* gp = gp0 + (kc + 1) * 128;
            ra = *(const float4*)gp;
            rb = *(const float4*)(gp + 4);
        }
        __syncthreads();
        if (kc < 7) {   // issue next-kc weight loads; land during this kc's MFMAs
#pragma unroll
            for (int ks = 0; ks < 4; ++ks)
#pragma unroll
                for (int nt = 0; nt < 2; ++nt)
                    bfr[(kc + 1) & 1][ks][nt] =
                        *(const short8*)(wp + ((((size_t)(wq4 * 2 + nt)) * 32 + ((kc + 1) * 4 + ks)) * 64 + lane) * 8);
        }
        const unsigned short* xb = xs[kc & 1];
#pragma unroll
        for (int ks = 0; ks < 4; ++ks) {
            short8 a[2];
#pragma unroll
            for (int mt = 0; mt < 2; ++mt)
                a[mt] = *(const short8*)(xb + (mt * 16 + lr) * 136 + ks * 32 + lk * 8);
#pragma unroll
            for (int mt = 0; mt < 2; ++mt)
#pragma unroll
                for (int nt = 0; nt < 2; ++nt)
                    acc[mt][nt] = MFMA16(a[mt], bfr[kc & 1][ks][nt], acc[mt][nt]);
        }
    }
    __syncthreads();
    // epilogue A: gate waves write sigmoid; fc waves combine -> h
    if (isg) {
#pragma unroll
        for (int mt = 0; mt < 2; ++mt)
#pragma unroll
            for (int nt = 0; nt < 2; ++nt) {
                int col = wq4 * 32 + nt * 16 + lr;
                float bb = bg[col];
#pragma unroll
                for (int r = 0; r < 4; ++r) {
                    float v = acc[mt][nt][r] + bb;
                    gbuf[(mt * 16 + lk * 4 + r) * 132 + col] =
                        __builtin_amdgcn_rcpf(1.0f + __builtin_amdgcn_exp2f(-1.4426950408889634f * v));
                }
            }
    }
    __syncthreads();
    if (!isg) {
#pragma unroll
        for (int mt = 0; mt < 2; ++mt)
#pragma unroll
            for (int nt = 0; nt < 2; ++nt) {
                int col = wq4 * 32 + nt * 16 + lr;
                float bb = bfc[col];
#pragma unroll
                for (int r = 0; r < 4; ++r) {
                    int row = mt * 16 + lk * 4 + r;
                    hs[row * 136 + col] = f2bf((acc[mt][nt][r] + bb) * gbuf[row * 132 + col]);
                }
            }
    }
    __syncthreads();

    // u[i] = h[i] @ wvo + c0 : thread t -> row t>>4, 8-elem chunk (t&15)*8
    {
        int row = tid >> 4, c = tid & 15;
        float s = 0.f;
#pragma unroll
        for (int e = 0; e < 8; ++e)
            s += bf2f(hs[row * 136 + c * 8 + e]) * wvo[c * 8 + e];
#pragma unroll
        for (int d = 1; d < 16; d <<= 1) s += __shfl_xor(s, d);
        if (c == 0) ug[i0 + row] = s + wvo[128];
    }

    // Phase B: q (w<4) | k (w>=4), 32 cols per wave, packed B
    floatx4 qacc[2][2];
#pragma unroll
    for (int mt = 0; mt < 2; ++mt)
#pragma unroll
        for (int nt = 0; nt < 2; ++nt) qacc[mt][nt] = (floatx4)0.0f;
    const unsigned short* wbp = (w < 4) ? wqp : wkp;
#pragma unroll
    for (int ks = 0; ks < 4; ++ks) {
        short8 a[2], b[2];
#pragma unroll
        for (int mt = 0; mt < 2; ++mt)
            a[mt] = *(const short8*)(hs + (mt * 16 + lr) * 136 + ks * 32 + lk * 8);
#pragma unroll
        for (int nt = 0; nt < 2; ++nt)
            b[nt] = *(const short8*)(wbp + ((((size_t)(wq4 * 2 + nt)) * 4 + ks) * 64 + lane) * 8);
#pragma unroll
        for (int mt = 0; mt < 2; ++mt)
#pragma unroll
            for (int nt = 0; nt < 2; ++nt)
                qacc[mt][nt] = MFMA16(a[mt], b[nt], qacc[mt][nt]);
    }
    // epilogue B: bias+scale -> LDS tile (xs reused: [0]=q, [1]=k)
    {
        unsigned short* dstl = xs[isg];
        const float* bb_ = (w < 4) ? bq : bk;
        const float sc = (w < 4) ? QSCALE : 1.0f;
#pragma unroll
        for (int mt = 0; mt < 2; ++mt)
#pragma unroll
            for (int nt = 0; nt < 2; ++nt) {
                int col = wq4 * 32 + nt * 16 + lr;
                float bb = bb_[col];
#pragma unroll
                for (int r = 0; r < 4; ++r)
                    dstl[(mt * 16 + lk * 4 + r) * 136 + col] = f2bf((qacc[mt][nt][r] + bb) * sc);
            }
    }
    __syncthreads();
    // cooperative packed store: 16 segments (sel,rtl,ks), wave w -> sel=w>>2, 2 ks each
    {
        int sel = w >> 2, p = w & 3;
        int rtl = p >> 1, ks2 = (p & 1) * 2;
        unsigned short* gdst = sel ? kpk : qpk;
        const unsigned short* src = xs[sel];
        size_t rt = (i0 >> 4) + rtl;
#pragma unroll
        for (int s = 0; s < 2; ++s) {
            int ks = ks2 + s;
            short8 v = *(const short8*)(src + (rtl * 16 + lr) * 136 + ks * 32 + lk * 8);
            *(short8*)(gdst + ((rt * 4 + ks) * 64 + lane) * 8) = v;
        }
    }
}

// ---------- K3: flash v16 — v12 structure + packed {num,lsum} finish ----------
// v12 (r6-verified best): 2-deep af ping-pong prefetch + setprio, NSPLIT=16.
// v16 change: nl[mt] = {numv,lsum}; finish does nl += {p,p} * {u[r],1.0}
// -> one v_pk_fma_f32 replaces fmac+add (-16 VALU insts/sub-tile off the
// measured 11.8us VALU critical path). numv half: identical fused fmac.
// lsum half: fma(p,1.0,l) == add (p*1.0 exact, single rounding) -> BIT-
// IDENTICAL results, same order. u2 pairs built in the hidden prefetch slot.
// launch_bounds(256,1): do NOT cap VGPR below ~160 (r6: spill storm).
__global__ __launch_bounds__(256, 1) void k_flash(const unsigned short* __restrict__ qp,
                                                  const unsigned short* __restrict__ kp,
                                                  const float* __restrict__ ug,
                                                  float2* __restrict__ pb) {
    const int tid = threadIdx.x;
    const int w = tid >> 6, lane = tid & 63;
    const int lr = lane & 15, lk = lane >> 4;
    const int rt0 = blockIdx.x * 16 + w * 4;    // q row-tile base

    // Q frags: 16 coalesced 1KB loads, live in registers
    short8 qf[4][4];
#pragma unroll
    for (int mt = 0; mt < 4; ++mt)
#pragma unroll
        for (int ks = 0; ks < 4; ++ks)
            qf[mt][ks] = *(const short8*)(qp + (((size_t)(rt0 + mt) * 4 + ks) * 64 + lane) * 8);

    float2v nl[4];                              // {numv, lsum} per mt
#pragma unroll
    for (int mt = 0; mt < 4; ++mt) nl[mt] = (float2v)0.0f;

    const int jt0 = blockIdx.y * 32;            // 32 j sub-tiles per split

    short8 af0[4], af1[4];
    float2v u20[4], u21[4];                     // {u[r], 1.0} pairs, even/odd tile
#pragma unroll
    for (int ks = 0; ks < 4; ++ks) {
        af0[ks] = *(const short8*)(kp + (((size_t)(jt0 + 0) * 4 + ks) * 64 + lane) * 8);
        af1[ks] = *(const short8*)(kp + (((size_t)(jt0 + 1) * 4 + ks) * 64 + lane) * 8);
    }
    {
        floatx4 t0 = *(const floatx4*)(ug + (jt0 + 0) * 16 + lk * 4);
        floatx4 t1 = *(const floatx4*)(ug + (jt0 + 1) * 16 + lk * 4);
#pragma unroll
        for (int r = 0; r < 4; ++r) {
            u20[r] = (float2v){t0[r], 1.0f};
            u21[r] = (float2v){t1[r], 1.0f};
        }
    }

    for (int tt = 0; tt < 16; ++tt) {
        const int tb = jt0 + tt * 2;
        // ---- even sub-tile (af0) ----
        {
            floatx4 sacc[4];
#pragma unroll
            for (int mt = 0; mt < 4; ++mt) sacc[mt] = (floatx4)0.0f;
            __builtin_amdgcn_s_setprio(1);
#pragma unroll
            for (int ks = 0; ks < 4; ++ks)
#pragma unroll
                for (int mt = 0; mt < 4; ++mt)
                    sacc[mt] = MFMA16(af0[ks], qf[mt][ks], sacc[mt]);
            __builtin_amdgcn_s_setprio(0);
            if (tt < 15) {   // refill af0 for t+2: in flight across odd sub-tile
#pragma unroll
                for (int ks = 0; ks < 4; ++ks)
                    af0[ks] = *(const short8*)(kp + (((size_t)(tb + 2) * 4 + ks) * 64 + lane) * 8);
            }
#pragma unroll
            for (int mt = 0; mt < 4; ++mt)
#pragma unroll
                for (int r = 0; r < 4; ++r) {
                    float p = __builtin_amdgcn_exp2f(sacc[mt][r]);
                    float2v pv = {p, p};
                    nl[mt] = pv * u20[r] + nl[mt];   // v_pk_fma_f32
                }
            if (tt < 15) {
                floatx4 t0 = *(const floatx4*)(ug + (tb + 2) * 16 + lk * 4);
#pragma unroll
                for (int r = 0; r < 4; ++r) u20[r] = (float2v){t0[r], 1.0f};
            }
        }
        // ---- odd sub-tile (af1) ----
        {
            floatx4 sacc[4];
#pragma unroll
            for (int mt = 0; mt < 4; ++mt) sacc[mt] = (floatx4)0.0f;
            __builtin_amdgcn_s_setprio(1);
#pragma unroll
            for (int ks = 0; ks < 4; ++ks)
#pragma unroll
                for (int mt = 0; mt < 4; ++mt)
                    sacc[mt] = MFMA16(af1[ks], qf[mt][ks], sacc[mt]);
            __builtin_amdgcn_s_setprio(0);
            if (tt < 15) {   // refill af1 for t+3: in flight across next even sub-tile
#pragma unroll
                for (int ks = 0; ks < 4; ++ks)
                    af1[ks] = *(const short8*)(kp + (((size_t)(tb + 3) * 4 + ks) * 64 + lane) * 8);
            }
#pragma unroll
            for (int mt = 0; mt < 4; ++mt)
#pragma unroll
                for (int r = 0; r < 4; ++r) {
                    float p = __builtin_amdgcn_exp2f(sacc[mt][r]);
                    float2v pv = {p, p};
                    nl[mt] = pv * u21[r] + nl[mt];   // v_pk_fma_f32
                }
            if (tt < 15) {
                floatx4 t1 = *(const floatx4*)(ug + (tb + 3) * 16 + lk * 4);
#pragma unroll
                for (int r = 0; r < 4; ++r) u21[r] = (float2v){t1[r], 1.0f};
            }
        }
    }

    // reduce over lk (lane bits 4,5); store transposed packed partial (n,l)
#pragma unroll
    for (int mt = 0; mt < 4; ++mt) {
        float n = nl[mt][0], l = nl[mt][1];
        n += __shfl_xor(n, 16); n += __shfl_xor(n, 32);
        l += __shfl_xor(l, 16); l += __shfl_xor(l, 32);
        if (lk == 0) {
            size_t row = (size_t)(rt0 + mt) * 16 + lr;
            pb[row * NSPLIT + blockIdx.y] = make_float2(n, l);
        }
    }
}

// ---------- K4: out[row] = (sum_s n_s) / (sum_s l_s) + b_out (r0 exact) ----------
__global__ __launch_bounds__(256) void k_out(const float2* __restrict__ pb,
                                             const float* __restrict__ bout,
                                             float* __restrict__ out) {
    int row = blockIdx.x * 256 + threadIdx.x;
    const float2* p = pb + (size_t)row * NSPLIT;
    float n = 0.f, l = 0.f;
#pragma unroll
    for (int s = 0; s < NSPLIT; ++s) {
        float2 v = p[s];
        n += v.x; l += v.y;
    }
    out[row] = n / l + bout[0];
}

// ---------- launch ----------
extern "C" void kernel_launch(void* const* d_in, const int* in_sizes, int n_in,
                              void* d_out, int out_size, void* d_ws, size_t ws_size,
                              hipStream_t stream) {
    const float* x    = (const float*)d_in[0];
    const float* Wfc  = (const float*)d_in[1];
    const float* bfc  = (const float*)d_in[2];
    const float* Wg   = (const float*)d_in[3];
    const float* bg   = (const float*)d_in[4];
    const float* Wq   = (const float*)d_in[5];
    const float* bq   = (const float*)d_in[6];
    const float* Wk   = (const float*)d_in[7];
    const float* bk   = (const float*)d_in[8];
    const float* Wv   = (const float*)d_in[9];
    const float* bv   = (const float*)d_in[10];
    const float* Wout = (const float*)d_in[11];
    const float* bout = (const float*)d_in[12];
    char* ws = (char*)d_ws;

    unsigned short* qb   = (unsigned short*)(ws + Q_OFF);
    unsigned short* kb   = (unsigned short*)(ws + K_OFF);
    float*          ub   = (float*)(ws + U_OFF);
    unsigned short* wfcp = (unsigned short*)(ws + WFCT_OFF);
    unsigned short* wgp  = (unsigned short*)(ws + WGT_OFF);
    unsigned short* wqp  = (unsigned short*)(ws + WQT_OFF);
    unsigned short* wkp  = (unsigned short*)(ws + WKT_OFF);
    float*          wvo  = (float*)(ws + WVO_OFF);
    float2*         pbb  = (float2*)(ws + PB_OFF);

    k_prep<<<1217, 256, 0, stream>>>(Wfc, Wg, Wq, Wk, Wv, Wout, bv, wfcp, wgp, wqp, wkp, wvo);
    k_gq<<<256, 512, 0, stream>>>(x, wfcp, wgp, bfc, bg, wqp, wkp, bq, bk, wvo, qb, kb, ub);

    dim3 gf(32, NSPLIT);
    k_flash<<<gf, 256, 0, stream>>>(qb, kb, ub, pbb);

    k_out<<<32, 256, 0, stream>>>(pbb, bout, (float*)d_out);
}

// Round 15
// 128.595 us; speedup vs baseline: 1.0205x; 1.0205x over previous
//
#include <hip/hip_runtime.h>

// ---------- types ----------
typedef short short8 __attribute__((ext_vector_type(8)));        // 8 bf16 MFMA A/B frag
typedef float floatx4 __attribute__((ext_vector_type(4)));       // MFMA C/D frag

__device__ __forceinline__ unsigned short f2bf(float f) {
    unsigned u = __float_as_uint(f);
    u += 0x7fffu + ((u >> 16) & 1u);   // RNE
    return (unsigned short)(u >> 16);
}
__device__ __forceinline__ float bf2f(unsigned short b) {
    unsigned u = (unsigned)b << 16;
    return __uint_as_float(u);
}

#define MFMA16(a, b, c)  __builtin_amdgcn_mfma_f32_16x16x32_bf16((a), (b), (c), 0, 0, 0)

// ---------- ws layout (bytes) ----------
// FINAL (r15): r6-exact configuration — the verified best (128.4 us).
// Session ledger: r0=134.3 | coop fusion=wash (drains not the cost) |
// v9 LDS-flash(32bar)=+4 | NSPLIT32(v8)=+2 | r6 latency fixes = 128.4 BEST
// (flash 2-deep reg prefetch + setprio; gq B-frag prefetch + kc unroll) |
// r7 gq-x2deep=+3.1 REV | r9 v13 global_load_lds staging=+8 REV |
// r11 NSPLIT32(v12)=+4.1 REV | r12 T15 intra-wave ping-pong=+2.7 REV |
// r13/14 pk_fma packed finish=wash.
// PROBES (r8/r10): fills=87us (2x256MB, untouchable) | T_flash=20.9
// (MfmaUtil 26.5 = 7.1us MFMA-busy = theoretical min for 17.2GF; VALU-busy
// 11.8 = critical path; FETCH 9.4MB; 0 bank conflicts) | T_gq=8.0 |
// prep+out+gaps=12.5. Remaining headroom ~5-8us spread across 3 components,
// each < fill-noise band (+-2-3us) -> unmeasurable; session converged.
static constexpr size_t Q_OFF    = 0;                    // q*QSCALE packed bf16 2 MB
static constexpr size_t K_OFF    = 2u << 20;             // k packed bf16        2 MB
static constexpr size_t U_OFF    = 4u << 20;             // u fp32 [8192]       32 KB
static constexpr size_t WFCT_OFF = U_OFF + 32768;        // W_fc packed bf16   256 KB
static constexpr size_t WGT_OFF  = WFCT_OFF + 262144;    // W_gate packed bf16
static constexpr size_t WQT_OFF  = WGT_OFF + 262144;     // W_q packed bf16     32 KB
static constexpr size_t WKT_OFF  = WQT_OFF + 32768;      // W_k packed bf16
static constexpr size_t WVO_OFF  = WKT_OFF + 32768;      // wvo fp32 [128] + c0
static constexpr size_t PB_OFF   = 5u << 20;             // partials float2 [8192][16] 1 MB

static constexpr int NSPLIT = 16;
// log2(e)/sqrt(128): folded into stored q so P = exp2(S)
static constexpr float QSCALE = 0.1275174308f;

// ---------- K1: weights -> MFMA-packed bf16 + wvo = W_v @ W_out GEMV (r0 exact) ----------
__global__ void k_prep(const float* __restrict__ wfc, const float* __restrict__ wg,
                       const float* __restrict__ wq, const float* __restrict__ wk,
                       const float* __restrict__ wv, const float* __restrict__ wout,
                       const float* __restrict__ bv,
                       unsigned short* __restrict__ dfc, unsigned short* __restrict__ dg,
                       unsigned short* __restrict__ dq, unsigned short* __restrict__ dk,
                       float* __restrict__ wvo) {
    if (blockIdx.x == 1216) {
        int t = threadIdx.x;
        if (t < 128) {
            float s = 0.f;
            for (int j = 0; j < 128; ++j) s += wv[t * 128 + j] * wout[j];
            wvo[t] = s;
        } else if (t == 128) {
            float s = 0.f;
            for (int j = 0; j < 128; ++j) s += bv[j] * wout[j];
            wvo[128] = s;   // c0
        }
        return;
    }
    int i = blockIdx.x * 256 + threadIdx.x;
    const float* s; unsigned short* d; int base, nchunk;
    if (i < 131072)      { s = wfc; d = dfc; nchunk = 32; base = 0; }
    else if (i < 262144) { s = wg;  d = dg;  nchunk = 32; base = 131072; }
    else if (i < 278528) { s = wq;  d = dq;  nchunk = 4;  base = 262144; }
    else if (i < 294912) { s = wk;  d = dk;  nchunk = 4;  base = 278528; }
    else return;
    int j = i - base;
    int kk = j >> 7, nn = j & 127;        // source W[kk][nn], row-major K x 128
    int t = nn >> 4, lr = nn & 15;
    int c = kk >> 5, lk = (kk >> 3) & 3, e = kk & 7;
    d[(((t * nchunk + c) * 64) + lr + 16 * lk) * 8 + e] = f2bf(s[j]);
}

// ---------- K2: fused gated-linear + QK + u (r6-exact, 128.4-verified) ----------
// kc-loop unrolled + B-frags register-prefetched one kc ahead, issued FIRST
// after the barrier -> each weight load gets a full MFMA-phase window.
// (r7's 2-deep x-prefetch regressed; 1-deep is correct here.)
__global__ __launch_bounds__(512) void k_gq(const float* __restrict__ x,
                                            const unsigned short* __restrict__ wfcp,
                                            const unsigned short* __restrict__ wgp,
                                            const float* __restrict__ bfc,
                                            const float* __restrict__ bg,
                                            const unsigned short* __restrict__ wqp,
                                            const unsigned short* __restrict__ wkp,
                                            const float* __restrict__ bq,
                                            const float* __restrict__ bk,
                                            const float* __restrict__ wvo,
                                            unsigned short* __restrict__ qpk,
                                            unsigned short* __restrict__ kpk,
                                            float* __restrict__ ug) {
    __shared__ __align__(16) unsigned short xs[2][32 * 136];
    __shared__ __align__(16) float gbuf[32 * 132];
    __shared__ __align__(16) unsigned short hs[32 * 136];
    const int tid = threadIdx.x;
    const int i0 = blockIdx.x * 32;
    const int w = tid >> 6, lane = tid & 63;
    const int lr = lane & 15, lk = lane >> 4;

    const int isg = (w >= 4);
    const int wq4 = w & 3;                 // 0..3: which 32-col group
    const unsigned short* wp = isg ? wgp : wfcp;

    floatx4 acc[2][2];
#pragma unroll
    for (int mt = 0; mt < 2; ++mt)
#pragma unroll
        for (int nt = 0; nt < 2; ++nt) acc[mt][nt] = (floatx4)0.0f;

    const int srow = tid >> 4, se = tid & 15;   // 32 rows x 16 thr, 8 floats each
    const float* gp0 = x + (size_t)(i0 + srow) * 1024 + se * 8;
    float4 ra = *(const float4*)gp0;
    float4 rb = *(const float4*)(gp0 + 4);

    // bfr[kc&1][ks][nt]: current/next kc weight frags (64 VGPR), preload kc=0
    short8 bfr[2][4][2];
#pragma unroll
    for (int ks = 0; ks < 4; ++ks)
#pragma unroll
        for (int nt = 0; nt < 2; ++nt)
            bfr[0][ks][nt] = *(const short8*)(wp + ((((size_t)(wq4 * 2 + nt)) * 32 + ks) * 64 + lane) * 8);

#pragma unroll
    for (int kc = 0; kc < 8; ++kc) {
        {   // commit prefetched chunk to LDS buf kc&1 (fp32 -> bf16)
            short8 t;
            unsigned short* tp = (unsigned short*)&t;
            tp[0] = f2bf(ra.x); tp[1] = f2bf(ra.y); tp[2] = f2bf(ra.z); tp[3] = f2bf(ra.w);
            tp[4] = f2bf(rb.x); tp[5] = f2bf(rb.y); tp[6] = f2bf(rb.z); tp[7] = f2bf(rb.w);
            *(short8*)(xs[kc & 1] + srow * 136 + se * 8) = t;
        }
        if (kc < 7) {
            const float* gp = gp0 + (kc + 1) * 128;
            ra = *(const float4*)gp;
            rb = *(const float4*)(gp + 4);
        }
        __syncthreads();
        if (kc < 7) {   // issue next-kc weight loads; land during this kc's MFMAs
#pragma unroll
            for (int ks = 0; ks < 4; ++ks)
#pragma unroll
                for (int nt = 0; nt < 2; ++nt)
                    bfr[(kc + 1) & 1][ks][nt] =
                        *(const short8*)(wp + ((((size_t)(wq4 * 2 + nt)) * 32 + ((kc + 1) * 4 + ks)) * 64 + lane) * 8);
        }
        const unsigned short* xb = xs[kc & 1];
#pragma unroll
        for (int ks = 0; ks < 4; ++ks) {
            short8 a[2];
#pragma unroll
            for (int mt = 0; mt < 2; ++mt)
                a[mt] = *(const short8*)(xb + (mt * 16 + lr) * 136 + ks * 32 + lk * 8);
#pragma unroll
            for (int mt = 0; mt < 2; ++mt)
#pragma unroll
                for (int nt = 0; nt < 2; ++nt)
                    acc[mt][nt] = MFMA16(a[mt], bfr[kc & 1][ks][nt], acc[mt][nt]);
        }
    }
    __syncthreads();
    // epilogue A: gate waves write sigmoid; fc waves combine -> h
    if (isg) {
#pragma unroll
        for (int mt = 0; mt < 2; ++mt)
#pragma unroll
            for (int nt = 0; nt < 2; ++nt) {
                int col = wq4 * 32 + nt * 16 + lr;
                float bb = bg[col];
#pragma unroll
                for (int r = 0; r < 4; ++r) {
                    float v = acc[mt][nt][r] + bb;
                    gbuf[(mt * 16 + lk * 4 + r) * 132 + col] =
                        __builtin_amdgcn_rcpf(1.0f + __builtin_amdgcn_exp2f(-1.4426950408889634f * v));
                }
            }
    }
    __syncthreads();
    if (!isg) {
#pragma unroll
        for (int mt = 0; mt < 2; ++mt)
#pragma unroll
            for (int nt = 0; nt < 2; ++nt) {
                int col = wq4 * 32 + nt * 16 + lr;
                float bb = bfc[col];
#pragma unroll
                for (int r = 0; r < 4; ++r) {
                    int row = mt * 16 + lk * 4 + r;
                    hs[row * 136 + col] = f2bf((acc[mt][nt][r] + bb) * gbuf[row * 132 + col]);
                }
            }
    }
    __syncthreads();

    // u[i] = h[i] @ wvo + c0 : thread t -> row t>>4, 8-elem chunk (t&15)*8
    {
        int row = tid >> 4, c = tid & 15;
        float s = 0.f;
#pragma unroll
        for (int e = 0; e < 8; ++e)
            s += bf2f(hs[row * 136 + c * 8 + e]) * wvo[c * 8 + e];
#pragma unroll
        for (int d = 1; d < 16; d <<= 1) s += __shfl_xor(s, d);
        if (c == 0) ug[i0 + row] = s + wvo[128];
    }

    // Phase B: q (w<4) | k (w>=4), 32 cols per wave, packed B
    floatx4 qacc[2][2];
#pragma unroll
    for (int mt = 0; mt < 2; ++mt)
#pragma unroll
        for (int nt = 0; nt < 2; ++nt) qacc[mt][nt] = (floatx4)0.0f;
    const unsigned short* wbp = (w < 4) ? wqp : wkp;
#pragma unroll
    for (int ks = 0; ks < 4; ++ks) {
        short8 a[2], b[2];
#pragma unroll
        for (int mt = 0; mt < 2; ++mt)
            a[mt] = *(const short8*)(hs + (mt * 16 + lr) * 136 + ks * 32 + lk * 8);
#pragma unroll
        for (int nt = 0; nt < 2; ++nt)
            b[nt] = *(const short8*)(wbp + ((((size_t)(wq4 * 2 + nt)) * 4 + ks) * 64 + lane) * 8);
#pragma unroll
        for (int mt = 0; mt < 2; ++mt)
#pragma unroll
            for (int nt = 0; nt < 2; ++nt)
                qacc[mt][nt] = MFMA16(a[mt], b[nt], qacc[mt][nt]);
    }
    // epilogue B: bias+scale -> LDS tile (xs reused: [0]=q, [1]=k)
    {
        unsigned short* dstl = xs[isg];
        const float* bb_ = (w < 4) ? bq : bk;
        const float sc = (w < 4) ? QSCALE : 1.0f;
#pragma unroll
        for (int mt = 0; mt < 2; ++mt)
#pragma unroll
            for (int nt = 0; nt < 2; ++nt) {
                int col = wq4 * 32 + nt * 16 + lr;
                float bb = bb_[col];
#pragma unroll
                for (int r = 0; r < 4; ++r)
                    dstl[(mt * 16 + lk * 4 + r) * 136 + col] = f2bf((qacc[mt][nt][r] + bb) * sc);
            }
    }
    __syncthreads();
    // cooperative packed store: 16 segments (sel,rtl,ks), wave w -> sel=w>>2, 2 ks each
    {
        int sel = w >> 2, p = w & 3;
        int rtl = p >> 1, ks2 = (p & 1) * 2;
        unsigned short* gdst = sel ? kpk : qpk;
        const unsigned short* src = xs[sel];
        size_t rt = (i0 >> 4) + rtl;
#pragma unroll
        for (int s = 0; s < 2; ++s) {
            int ks = ks2 + s;
            short8 v = *(const short8*)(src + (rtl * 16 + lr) * 136 + ks * 32 + lk * 8);
            *(short8*)(gdst + ((rt * 4 + ks) * 64 + lane) * 8) = v;
        }
    }
}

// ---------- K3: flash v12 — r6-exact (2-deep reg prefetch + setprio; BEST) ----------
// Barrier-free, per-wave register pipeline: ping-pong af0/af1 K-frag buffers
// (window 1.5-2 sub-tiles ~300-500cyc covers L2-under-load latency);
// setprio(1) around MFMA cluster (T5, positive for independent attn waves).
// Probed regime: MFMA-busy at theoretical min; VALU critical path;
// LDS staging / more TLP / intra-wave ping-pong / pk_fma all refuted.
// launch_bounds(256,1): ~160 VGPR — do NOT cap below (r6: spill storm).
__global__ __launch_bounds__(256, 1) void k_flash(const unsigned short* __restrict__ qp,
                                                  const unsigned short* __restrict__ kp,
                                                  const float* __restrict__ ug,
                                                  float2* __restrict__ pb) {
    const int tid = threadIdx.x;
    const int w = tid >> 6, lane = tid & 63;
    const int lr = lane & 15, lk = lane >> 4;
    const int rt0 = blockIdx.x * 16 + w * 4;    // q row-tile base

    // Q frags: 16 coalesced 1KB loads, live in registers
    short8 qf[4][4];
#pragma unroll
    for (int mt = 0; mt < 4; ++mt)
#pragma unroll
        for (int ks = 0; ks < 4; ++ks)
            qf[mt][ks] = *(const short8*)(qp + (((size_t)(rt0 + mt) * 4 + ks) * 64 + lane) * 8);

    float numv[4] = {0.f, 0.f, 0.f, 0.f};
    float lsum[4] = {0.f, 0.f, 0.f, 0.f};

    const int jt0 = blockIdx.y * 32;            // 32 j sub-tiles per split

    short8 af0[4], af1[4];
    floatx4 uu0, uu1;
#pragma unroll
    for (int ks = 0; ks < 4; ++ks) {
        af0[ks] = *(const short8*)(kp + (((size_t)(jt0 + 0) * 4 + ks) * 64 + lane) * 8);
        af1[ks] = *(const short8*)(kp + (((size_t)(jt0 + 1) * 4 + ks) * 64 + lane) * 8);
    }
    uu0 = *(const floatx4*)(ug + (jt0 + 0) * 16 + lk * 4);
    uu1 = *(const floatx4*)(ug + (jt0 + 1) * 16 + lk * 4);

    for (int tt = 0; tt < 16; ++tt) {
        const int tb = jt0 + tt * 2;
        // ---- even sub-tile (af0) ----
        {
            floatx4 sacc[4];
#pragma unroll
            for (int mt = 0; mt < 4; ++mt) sacc[mt] = (floatx4)0.0f;
            __builtin_amdgcn_s_setprio(1);
#pragma unroll
            for (int ks = 0; ks < 4; ++ks)
#pragma unroll
                for (int mt = 0; mt < 4; ++mt)
                    sacc[mt] = MFMA16(af0[ks], qf[mt][ks], sacc[mt]);
            __builtin_amdgcn_s_setprio(0);
            if (tt < 15) {   // refill af0 for t+2: in flight across odd sub-tile
#pragma unroll
                for (int ks = 0; ks < 4; ++ks)
                    af0[ks] = *(const short8*)(kp + (((size_t)(tb + 2) * 4 + ks) * 64 + lane) * 8);
            }
#pragma unroll
            for (int mt = 0; mt < 4; ++mt)
#pragma unroll
                for (int r = 0; r < 4; ++r) {
                    float p = __builtin_amdgcn_exp2f(sacc[mt][r]);
                    numv[mt] += p * uu0[r];
                    lsum[mt] += p;
                }
            if (tt < 15) uu0 = *(const floatx4*)(ug + (tb + 2) * 16 + lk * 4);
        }
        // ---- odd sub-tile (af1) ----
        {
            floatx4 sacc[4];
#pragma unroll
            for (int mt = 0; mt < 4; ++mt) sacc[mt] = (floatx4)0.0f;
            __builtin_amdgcn_s_setprio(1);
#pragma unroll
            for (int ks = 0; ks < 4; ++ks)
#pragma unroll
                for (int mt = 0; mt < 4; ++mt)
                    sacc[mt] = MFMA16(af1[ks], qf[mt][ks], sacc[mt]);
            __builtin_amdgcn_s_setprio(0);
            if (tt < 15) {   // refill af1 for t+3: in flight across next even sub-tile
#pragma unroll
                for (int ks = 0; ks < 4; ++ks)
                    af1[ks] = *(const short8*)(kp + (((size_t)(tb + 3) * 4 + ks) * 64 + lane) * 8);
            }
#pragma unroll
            for (int mt = 0; mt < 4; ++mt)
#pragma unroll
                for (int r = 0; r < 4; ++r) {
                    float p = __builtin_amdgcn_exp2f(sacc[mt][r]);
                    numv[mt] += p * uu1[r];
                    lsum[mt] += p;
                }
            if (tt < 15) uu1 = *(const floatx4*)(ug + (tb + 3) * 16 + lk * 4);
        }
    }

    // reduce over lk (lane bits 4,5); store transposed packed partial (n,l)
#pragma unroll
    for (int mt = 0; mt < 4; ++mt) {
        float n = numv[mt], l = lsum[mt];
        n += __shfl_xor(n, 16); n += __shfl_xor(n, 32);
        l += __shfl_xor(l, 16); l += __shfl_xor(l, 32);
        if (lk == 0) {
            size_t row = (size_t)(rt0 + mt) * 16 + lr;
            pb[row * NSPLIT + blockIdx.y] = make_float2(n, l);
        }
    }
}

// ---------- K4: out[row] = (sum_s n_s) / (sum_s l_s) + b_out (r0 exact) ----------
__global__ __launch_bounds__(256) void k_out(const float2* __restrict__ pb,
                                             const float* __restrict__ bout,
                                             float* __restrict__ out) {
    int row = blockIdx.x * 256 + threadIdx.x;
    const float2* p = pb + (size_t)row * NSPLIT;
    float n = 0.f, l = 0.f;
#pragma unroll
    for (int s = 0; s < NSPLIT; ++s) {
        float2 v = p[s];
        n += v.x; l += v.y;
    }
    out[row] = n / l + bout[0];
}

// ---------- launch ----------
extern "C" void kernel_launch(void* const* d_in, const int* in_sizes, int n_in,
                              void* d_out, int out_size, void* d_ws, size_t ws_size,
                              hipStream_t stream) {
    const float* x    = (const float*)d_in[0];
    const float* Wfc  = (const float*)d_in[1];
    const float* bfc  = (const float*)d_in[2];
    const float* Wg   = (const float*)d_in[3];
    const float* bg   = (const float*)d_in[4];
    const float* Wq   = (const float*)d_in[5];
    const float* bq   = (const float*)d_in[6];
    const float* Wk   = (const float*)d_in[7];
    const float* bk   = (const float*)d_in[8];
    const float* Wv   = (const float*)d_in[9];
    const float* bv   = (const float*)d_in[10];
    const float* Wout = (const float*)d_in[11];
    const float* bout = (const float*)d_in[12];
    char* ws = (char*)d_ws;

    unsigned short* qb   = (unsigned short*)(ws + Q_OFF);
    unsigned short* kb   = (unsigned short*)(ws + K_OFF);
    float*          ub   = (float*)(ws + U_OFF);
    unsigned short* wfcp = (unsigned short*)(ws + WFCT_OFF);
    unsigned short* wgp  = (unsigned short*)(ws + WGT_OFF);
    unsigned short* wqp  = (unsigned short*)(ws + WQT_OFF);
    unsigned short* wkp  = (unsigned short*)(ws + WKT_OFF);
    float*          wvo  = (float*)(ws + WVO_OFF);
    float2*         pbb  = (float2*)(ws + PB_OFF);

    k_prep<<<1217, 256, 0, stream>>>(Wfc, Wg, Wq, Wk, Wv, Wout, bv, wfcp, wgp, wqp, wkp, wvo);
    k_gq<<<256, 512, 0, stream>>>(x, wfcp, wgp, bfc, bg, wqp, wkp, bq, bk, wvo, qb, kb, ub);

    dim3 gf(32, NSPLIT);
    k_flash<<<gf, 256, 0, stream>>>(qb, kb, ub, pbb);

    k_out<<<32, 256, 0, stream>>>(pbb, bout, (float*)d_out);
}